// Round 2
// baseline (2607.433 us; speedup 1.0000x reference)
//
#include <hip/hip_runtime.h>

typedef _Float16 half_t;
typedef __attribute__((ext_vector_type(8))) _Float16 h8_t;
typedef __attribute__((ext_vector_type(2))) _Float16 h2_t;
typedef __attribute__((ext_vector_type(4))) float f4_t;

#define NN      50000
#define NE      800000
#define NG      256
#define NODE_IN 92
#define EDGE_IN 41

__device__ __forceinline__ float softplus_f(float x) {
  return fmaxf(x, 0.0f) + __logf(1.0f + __expf(-fabsf(x)));
}

// ---------- weight prep: fp32 [K][N] -> f16 [N][K] (per conv layer) ----------
__global__ __launch_bounds__(256) void prep_weights_kernel(
    const float* __restrict__ e1W, const float* __restrict__ e2W,
    const float* __restrict__ nW,
    half_t* __restrict__ W1T, half_t* __restrict__ W2T, half_t* __restrict__ WnT)
{
  int idx = blockIdx.x * 256 + threadIdx.x;        // 0 .. 491519 (exact grid)
  if (idx < 294912) {                              // W1T: 3 x 256 x 384
    int i = idx / 98304, rem = idx % 98304;
    int n = rem / 384, k = rem % 384;
    W1T[idx] = (half_t)e1W[i * 98304 + k * 256 + n];
  } else if (idx < 393216) {                       // W2T: 3 x 128 x 256
    int o = idx - 294912;
    int i = o / 32768, rem = o % 32768;
    int n = rem / 256, k = rem % 256;
    W2T[o] = (half_t)e2W[i * 32768 + k * 128 + n];
  } else {                                         // WnT: 3 x 128 x 256
    int o = idx - 393216;
    int i = o / 32768, rem = o % 32768;
    int n = rem / 256, k = rem % 256;
    WnT[o] = (half_t)nW[i * 32768 + k * 128 + n];
  }
}

// ---------- node embedding: h = x @ node_W + node_b (fp32 + f16 copy) ----------
__global__ __launch_bounds__(256) void node_embed_kernel(
    const float* __restrict__ x, const float* __restrict__ W,
    const float* __restrict__ bias, float* __restrict__ hf,
    half_t* __restrict__ h16)
{
  __shared__ float xs[16 * NODE_IN];
  int n0 = blockIdx.x * 16;
  for (int i = threadIdx.x; i < 16 * NODE_IN; i += 256)
    xs[i] = x[(size_t)n0 * NODE_IN + i];
  __syncthreads();
  int ch = threadIdx.x & 127, g = threadIdx.x >> 7;
  float acc[8] = {0.f,0.f,0.f,0.f,0.f,0.f,0.f,0.f};
  for (int k = 0; k < NODE_IN; ++k) {
    float w = W[k * 128 + ch];
    #pragma unroll
    for (int u = 0; u < 8; ++u) acc[u] += xs[(g + 2*u) * NODE_IN + k] * w;
  }
  float bv = bias[ch];
  #pragma unroll
  for (int u = 0; u < 8; ++u) {
    int n = n0 + g + 2*u;
    float v = acc[u] + bv;
    hf[(size_t)n*128 + ch] = v;
    h16[(size_t)n*128 + ch] = (half_t)v;
  }
}

// ---------- edge embedding: ea = edge_attr @ edge_W + edge_b (f16) ----------
__global__ __launch_bounds__(256) void edge_embed_kernel(
    const float* __restrict__ ea, const float* __restrict__ W,
    const float* __restrict__ bias, half_t* __restrict__ ea16)
{
  __shared__ float es[16 * EDGE_IN];
  int e0 = blockIdx.x * 16;
  for (int i = threadIdx.x; i < 16 * EDGE_IN; i += 256)
    es[i] = ea[(size_t)e0 * EDGE_IN + i];
  __syncthreads();
  int ch = threadIdx.x & 127, g = threadIdx.x >> 7;
  float acc[8] = {0.f,0.f,0.f,0.f,0.f,0.f,0.f,0.f};
  for (int k = 0; k < EDGE_IN; ++k) {
    float w = W[k * 128 + ch];
    #pragma unroll
    for (int u = 0; u < 8; ++u) acc[u] += es[(g + 2*u) * EDGE_IN + k] * w;
  }
  float bv = bias[ch];
  #pragma unroll
  for (int u = 0; u < 8; ++u) {
    int e = e0 + g + 2*u;
    ea16[(size_t)e*128 + ch] = (half_t)(acc[u] + bv);
  }
}

// ---------- CSR build (by destination node = edge_index[1]) ----------
__global__ __launch_bounds__(256) void csr_count_kernel(
    const int* __restrict__ col, int* __restrict__ cnt)
{
  int e = blockIdx.x * 256 + threadIdx.x;
  atomicAdd(&cnt[col[e]], 1);
}

__global__ __launch_bounds__(1024) void csr_scan_kernel(
    const int* __restrict__ cnt, int* __restrict__ starts, int* __restrict__ cur)
{
  __shared__ int buf[1024];
  int tid = threadIdx.x;
  int base = 0;
  for (int c = 0; c < 49; ++c) {
    int i = c * 1024 + tid;
    int v = (i < NN) ? cnt[i] : 0;
    buf[tid] = v;
    __syncthreads();
    for (int off = 1; off < 1024; off <<= 1) {
      int t2 = (tid >= off) ? buf[tid - off] : 0;
      __syncthreads();
      buf[tid] += t2;
      __syncthreads();
    }
    int incl = buf[tid];
    int total = buf[1023];
    if (i < NN) { int st = base + incl - v; starts[i] = st; cur[i] = st; }
    base += total;
    __syncthreads();
  }
  if (tid == 0) starts[NN] = base;
}

__global__ __launch_bounds__(256) void csr_fill_kernel(
    const int* __restrict__ col, int* __restrict__ cur, int* __restrict__ eid)
{
  int e = blockIdx.x * 256 + threadIdx.x;
  int pos = atomicAdd(&cur[col[e]], 1);
  eid[pos] = e;
}

// ---------- fused edge MLP (swapped-operand MFMA):
//   P^T = W1^T · [h_row|h_col|ea]^T ; out^T = W2^T · P^T ; coalesced ee2 store
__global__ __launch_bounds__(256, 4) void conv_edge_kernel(
    const half_t* __restrict__ h16, const half_t* __restrict__ ea16,
    const int* __restrict__ eidx,
    const half_t* __restrict__ W1T, const float* __restrict__ b1,
    const half_t* __restrict__ W2T, const float* __restrict__ b2,
    half_t* __restrict__ ee2)
{
  __shared__ char smem[64 * 256 * 2];   // 32 KB: A-features (0-255), then P, then out
  const int tid = threadIdx.x;
  const int e0 = blockIdx.x * 64;

  // gather [h[row] | h[col]] -> LDS [edge][256], row stride 512B, XOR swizzle
  #pragma unroll
  for (int it = 0; it < 8; ++it) {
    int idx = tid + it * 256;           // 0..2047 = 64 edges x 32 chunks(16B)
    int e = idx >> 5, c = idx & 31;
    int node = eidx[(c < 16 ? 0 : NE) + e0 + e];
    uint4 v = *reinterpret_cast<const uint4*>(h16 + (size_t)node * 128 + (c & 15) * 8);
    unsigned o = (unsigned)(e * 512 + c * 16) ^ (unsigned)((e & 7) << 4);
    *reinterpret_cast<uint4*>(smem + o) = v;
  }
  __syncthreads();

  const int lane = tid & 63, wave = tid >> 6;
  const int lr = lane & 15, lg = lane >> 4;

  // GEMM1 (swapped): D[channel][edge]; wave owns channels [wave*64, +64)
  const half_t* W1w = W1T + (size_t)(wave * 64) * 384;
  f4_t acc[4][4] = {};
  for (int ks = 0; ks < 8; ++ks) {      // features 0..255 from LDS
    h8_t a[4], b[4];
    #pragma unroll
    for (int m = 0; m < 4; ++m)
      a[m] = *reinterpret_cast<const h8_t*>(W1w + (size_t)(m * 16 + lr) * 384 + ks * 32 + lg * 8);
    #pragma unroll
    for (int n = 0; n < 4; ++n) {
      int e = n * 16 + lr;
      unsigned o = (unsigned)(e * 512 + ks * 64 + lg * 16) ^ (unsigned)((e & 7) << 4);
      b[n] = *reinterpret_cast<const h8_t*>(smem + o);
    }
    #pragma unroll
    for (int m = 0; m < 4; ++m)
      #pragma unroll
      for (int n = 0; n < 4; ++n)
        acc[m][n] = __builtin_amdgcn_mfma_f32_16x16x32_f16(a[m], b[n], acc[m][n], 0, 0, 0);
  }
  for (int ks = 8; ks < 12; ++ks) {     // features 256..383 = ea, direct from global
    h8_t a[4], b[4];
    #pragma unroll
    for (int m = 0; m < 4; ++m)
      a[m] = *reinterpret_cast<const h8_t*>(W1w + (size_t)(m * 16 + lr) * 384 + ks * 32 + lg * 8);
    #pragma unroll
    for (int n = 0; n < 4; ++n)
      b[n] = *reinterpret_cast<const h8_t*>(ea16 + (size_t)(e0 + n * 16 + lr) * 128 + (ks - 8) * 32 + lg * 8);
    #pragma unroll
    for (int m = 0; m < 4; ++m)
      #pragma unroll
      for (int n = 0; n < 4; ++n)
        acc[m][n] = __builtin_amdgcn_mfma_f32_16x16x32_f16(a[m], b[n], acc[m][n], 0, 0, 0);
  }
  __syncthreads();   // all waves done reading A-tile

  // epilogue1: softplus -> P[edge][256ch] in LDS (packed f16 pairs)
  #pragma unroll
  for (int m = 0; m < 4; ++m) {
    int chb = wave * 64 + m * 16 + lg * 4;
    float bb0 = b1[chb + 0], bb1 = b1[chb + 1], bb2 = b1[chb + 2], bb3 = b1[chb + 3];
    #pragma unroll
    for (int n = 0; n < 4; ++n) {
      int e = n * 16 + lr;
      float v0 = softplus_f(acc[m][n][0] + bb0);
      float v1 = softplus_f(acc[m][n][1] + bb1);
      float v2 = softplus_f(acc[m][n][2] + bb2);
      float v3 = softplus_f(acc[m][n][3] + bb3);
      unsigned p01 = __builtin_bit_cast(unsigned, __builtin_amdgcn_cvt_pkrtz(v0, v1));
      unsigned p23 = __builtin_bit_cast(unsigned, __builtin_amdgcn_cvt_pkrtz(v2, v3));
      unsigned o = (unsigned)(e * 512 + chb * 2) ^ (unsigned)((e & 7) << 4);
      *reinterpret_cast<unsigned*>(smem + o) = p01;
      *reinterpret_cast<unsigned*>(smem + o + 4) = p23;
    }
  }
  __syncthreads();

  // GEMM2 (swapped): D[ch2][edge]; wave owns ch2 [wave*32, +32)
  const half_t* W2w = W2T + (size_t)(wave * 32) * 256;
  f4_t acc2[2][4] = {};
  for (int ks = 0; ks < 8; ++ks) {
    h8_t a2[2], b2v[4];
    #pragma unroll
    for (int m = 0; m < 2; ++m)
      a2[m] = *reinterpret_cast<const h8_t*>(W2w + (size_t)(m * 16 + lr) * 256 + ks * 32 + lg * 8);
    #pragma unroll
    for (int n = 0; n < 4; ++n) {
      int e = n * 16 + lr;
      unsigned o = (unsigned)(e * 512 + ks * 64 + lg * 16) ^ (unsigned)((e & 7) << 4);
      b2v[n] = *reinterpret_cast<const h8_t*>(smem + o);
    }
    #pragma unroll
    for (int m = 0; m < 2; ++m)
      #pragma unroll
      for (int n = 0; n < 4; ++n)
        acc2[m][n] = __builtin_amdgcn_mfma_f32_16x16x32_f16(a2[m], b2v[n], acc2[m][n], 0, 0, 0);
  }
  __syncthreads();   // all waves done reading P

  // epilogue2: softplus -> out[edge][128] in LDS (stride 256B, swizzled)
  #pragma unroll
  for (int m = 0; m < 2; ++m) {
    int chb = wave * 32 + m * 16 + lg * 4;
    float bb0 = b2[chb + 0], bb1 = b2[chb + 1], bb2 = b2[chb + 2], bb3 = b2[chb + 3];
    #pragma unroll
    for (int n = 0; n < 4; ++n) {
      int e = n * 16 + lr;
      float v0 = softplus_f(acc2[m][n][0] + bb0);
      float v1 = softplus_f(acc2[m][n][1] + bb1);
      float v2 = softplus_f(acc2[m][n][2] + bb2);
      float v3 = softplus_f(acc2[m][n][3] + bb3);
      unsigned p01 = __builtin_bit_cast(unsigned, __builtin_amdgcn_cvt_pkrtz(v0, v1));
      unsigned p23 = __builtin_bit_cast(unsigned, __builtin_amdgcn_cvt_pkrtz(v2, v3));
      unsigned o = (unsigned)(e * 256 + chb * 2) ^ (unsigned)((e & 7) << 4);
      *reinterpret_cast<unsigned*>(smem + o) = p01;
      *reinterpret_cast<unsigned*>(smem + o + 4) = p23;
    }
  }
  __syncthreads();

  // coalesced writeout: 64 edges x 256B
  #pragma unroll
  for (int it = 0; it < 4; ++it) {
    int idx = tid + it * 256;           // 0..1023 = 64 edges x 16 chunks
    int e = idx >> 4, c = idx & 15;
    unsigned o = (unsigned)(e * 256 + c * 16) ^ (unsigned)((e & 7) << 4);
    uint4 v = *reinterpret_cast<const uint4*>(smem + o);
    *reinterpret_cast<uint4*>(ee2 + (size_t)(e0 + e) * 128 + c * 8) = v;
  }
}

// ---------- aggregation: aggr[n] = sum over in-edges of ee2 (CSR gather) ----------
__global__ __launch_bounds__(64) void aggr_kernel(
    const int* __restrict__ starts, const int* __restrict__ eid,
    const half_t* __restrict__ ee2, half_t* __restrict__ aggr16)
{
  int n = blockIdx.x, t = threadIdx.x;
  int s = starts[n], epos = starts[n + 1];
  float a0 = 0.f, a1 = 0.f;
  for (int i = s; i < epos; ++i) {
    int e = eid[i];
    unsigned v = *reinterpret_cast<const unsigned*>(ee2 + (size_t)e * 128 + t * 2);
    union { unsigned u; _Float16 h[2]; } cv; cv.u = v;
    a0 += (float)cv.h[0];
    a1 += (float)cv.h[1];
  }
  union { unsigned u; _Float16 h[2]; } ov;
  ov.h[0] = (_Float16)a0; ov.h[1] = (_Float16)a1;
  *reinterpret_cast<unsigned*>(aggr16 + (size_t)n * 128 + t * 2) = ov.u;
}

// ---------- node update: h = sp([h|aggr] @ Wn + bn) + h ----------
__global__ __launch_bounds__(256, 2) void conv_node_kernel(
    half_t* __restrict__ h16, const half_t* __restrict__ aggr16,
    const half_t* __restrict__ WnT, const float* __restrict__ bn,
    float* __restrict__ hf)
{
  __shared__ char smem[64 * 256 * 2];   // 32 KB A = [h | aggr] f16, swizzled
  const int tid = threadIdx.x;
  const int n0 = blockIdx.x * 64;

  #pragma unroll
  for (int it = 0; it < 8; ++it) {
    int idx = tid + it * 256;          // 0..2047 = 64 rows x 32 chunks
    int r = idx >> 5, c = idx & 31;
    int node = n0 + r;
    uint4 v = make_uint4(0u, 0u, 0u, 0u);
    if (node < NN) {
      const half_t* src = (c < 16) ? (h16   + (size_t)node * 128 + c * 8)
                                   : (aggr16 + (size_t)node * 128 + (c - 16) * 8);
      v = *reinterpret_cast<const uint4*>(src);
    }
    unsigned o = (unsigned)(r * 512 + c * 16) ^ (unsigned)((r & 7) << 4);
    *reinterpret_cast<uint4*>(smem + o) = v;
  }
  __syncthreads();

  const int lane = tid & 63, wave = tid >> 6;
  const int lr = lane & 15, lg = lane >> 4;
  const int c0 = wave * 32;
  f4_t acc[4][2] = {};
  for (int ks = 0; ks < 8; ++ks) {
    h8_t a[4], b[2];
    #pragma unroll
    for (int m = 0; m < 4; ++m) {
      int row = m * 16 + lr;
      unsigned o = (unsigned)(row * 512 + ks * 64 + lg * 16) ^ (unsigned)((row & 7) << 4);
      a[m] = *reinterpret_cast<const h8_t*>(smem + o);
    }
    #pragma unroll
    for (int n = 0; n < 2; ++n) {
      int colw = c0 + n * 16 + lr;
      b[n] = *reinterpret_cast<const h8_t*>(WnT + (size_t)colw * 256 + ks * 32 + lg * 8);
    }
    #pragma unroll
    for (int m = 0; m < 4; ++m)
      #pragma unroll
      for (int n = 0; n < 2; ++n)
        acc[m][n] = __builtin_amdgcn_mfma_f32_16x16x32_f16(a[m], b[n], acc[m][n], 0, 0, 0);
  }
  #pragma unroll
  for (int m = 0; m < 4; ++m)
    #pragma unroll
    for (int n = 0; n < 2; ++n)
      #pragma unroll
      for (int r = 0; r < 4; ++r) {
        int row = m * 16 + lg * 4 + r;
        int col = c0 + n * 16 + lr;
        int node = n0 + row;
        if (node < NN) {
          float v = softplus_f(acc[m][n][r] + bn[col]) + hf[(size_t)node * 128 + col];
          hf[(size_t)node * 128 + col] = v;
          h16[(size_t)node * 128 + col] = (half_t)v;
        }
      }
}

// ---------- mean pool (run-length compressed atomics; batch is sorted) ----------
__global__ __launch_bounds__(128) void pool_kernel(
    const float* __restrict__ hf, const int* __restrict__ batch,
    float* __restrict__ gsum, int* __restrict__ gcnt)
{
  int t = threadIdx.x;
  int n0 = blockIdx.x * 16;
  float acc = 0.f;
  int curb = batch[n0];
  for (int i = 0; i < 16; ++i) {
    int n = n0 + i;
    int b = batch[n];
    if (b != curb) { atomicAdd(&gsum[curb * 128 + t], acc); acc = 0.f; curb = b; }
    acc += hf[(size_t)n * 128 + t];
  }
  atomicAdd(&gsum[curb * 128 + t], acc);
  if (t == 0) {
    int c = 0, cb = batch[n0];
    for (int i = 0; i < 16; ++i) {
      int b = batch[n0 + i];
      if (b != cb) { atomicAdd(&gcnt[cb], c); c = 0; cb = b; }
      ++c;
    }
    atomicAdd(&gcnt[cb], c);
  }
}

// ---------- shared MLP + task heads (one block per graph) ----------
__global__ __launch_bounds__(128) void heads_kernel(
    const float* __restrict__ gsum, const int* __restrict__ gcnt,
    const float* __restrict__ sW1, const float* __restrict__ sb1,
    const float* __restrict__ sW2, const float* __restrict__ sb2,
    const float* __restrict__ hW, const float* __restrict__ hb,
    const float* __restrict__ hoW, const float* __restrict__ hob,
    float* __restrict__ out)
{
  int b = blockIdx.x, t = threadIdx.x;
  __shared__ float va[128], vb[128], vc[128], red[128];
  float inv = 1.0f / fmaxf((float)gcnt[b], 1.0f);
  va[t] = gsum[b * 128 + t] * inv;
  __syncthreads();
  { float a = 0.f;
    for (int k = 0; k < 128; ++k) a += va[k] * sW1[k * 128 + t];
    float r = softplus_f(a + sb1[t]);
    __syncthreads(); vb[t] = r; __syncthreads(); }
  { float a = 0.f;
    for (int k = 0; k < 128; ++k) a += vb[k] * sW2[k * 128 + t];
    float r = softplus_f(a + sb2[t]);
    __syncthreads(); va[t] = r; __syncthreads(); }   // va = g2 (kept live)
  for (int p = 0; p < 3; ++p) {
    { float a = 0.f;
      for (int k = 0; k < 128; ++k) a += va[k] * hW[((p * 2 + 0) * 128 + k) * 128 + t];
      float r = softplus_f(a + hb[(p * 2 + 0) * 128 + t]);
      __syncthreads(); vb[t] = r; __syncthreads(); }
    { float a = 0.f;
      for (int k = 0; k < 128; ++k) a += vb[k] * hW[((p * 2 + 1) * 128 + k) * 128 + t];
      float r = softplus_f(a + hb[(p * 2 + 1) * 128 + t]);
      __syncthreads(); vc[t] = r; __syncthreads(); }
    red[t] = vc[t] * hoW[p * 128 + t];
    __syncthreads();
    for (int s = 64; s > 0; s >>= 1) {
      if (t < s) red[t] += red[t + s];
      __syncthreads();
    }
    if (t == 0) out[p * NG + b] = red[0] + hob[p];
    __syncthreads();
  }
}

extern "C" void kernel_launch(void* const* d_in, const int* in_sizes, int n_in,
                              void* d_out, int out_size, void* d_ws, size_t ws_size,
                              hipStream_t stream)
{
  const float* x     = (const float*)d_in[0];
  const float* eattr = (const float*)d_in[1];
  const float* nodeW = (const float*)d_in[2];
  const float* nodeb = (const float*)d_in[3];
  const float* edgeW = (const float*)d_in[4];
  const float* edgeb = (const float*)d_in[5];
  const float* e1W   = (const float*)d_in[6];
  const float* e1b   = (const float*)d_in[7];
  const float* e2W   = (const float*)d_in[8];
  const float* e2b   = (const float*)d_in[9];
  const float* nW    = (const float*)d_in[10];
  const float* nb    = (const float*)d_in[11];
  const float* sW1   = (const float*)d_in[12];
  const float* sb1   = (const float*)d_in[13];
  const float* sW2   = (const float*)d_in[14];
  const float* sb2   = (const float*)d_in[15];
  const float* hW    = (const float*)d_in[16];
  const float* hb    = (const float*)d_in[17];
  const float* hoW   = (const float*)d_in[18];
  const float* hob   = (const float*)d_in[19];
  const int*   eidx  = (const int*)d_in[20];
  const int*   batch = (const int*)d_in[21];
  float* out = (float*)d_out;

  char* base = (char*)d_ws;
  size_t woff = 0;
  auto alloc = [&](size_t bytes) -> char* {
    char* r = base + woff;
    woff = (woff + bytes + 255) & ~(size_t)255;
    return r;
  };
  float*  hf     = (float*) alloc((size_t)NN * 128 * 4);
  half_t* h16    = (half_t*)alloc((size_t)NN * 128 * 2);
  half_t* ea16   = (half_t*)alloc((size_t)NE * 128 * 2);
  half_t* ee2    = (half_t*)alloc((size_t)NE * 128 * 2);
  half_t* aggr16 = (half_t*)alloc((size_t)NN * 128 * 2);
  half_t* W1T    = (half_t*)alloc((size_t)3 * 256 * 384 * 2);
  half_t* W2T    = (half_t*)alloc((size_t)3 * 128 * 256 * 2);
  half_t* WnT    = (half_t*)alloc((size_t)3 * 128 * 256 * 2);
  int* cnt    = (int*)alloc((size_t)NN * 4);
  int* starts = (int*)alloc((size_t)(NN + 1) * 4);
  int* cur    = (int*)alloc((size_t)NN * 4);
  int* eid    = (int*)alloc((size_t)NE * 4);
  float* gsum = (float*)alloc((size_t)NG * 128 * 4);
  int*   gcnt = (int*)alloc((size_t)NG * 4);
  if (woff > ws_size) return;   // workspace too small: launch nothing (fail loud)

  hipMemsetAsync(cnt, 0, (size_t)NN * 4, stream);
  hipMemsetAsync(gsum, 0, (size_t)NG * 128 * 4, stream);
  hipMemsetAsync(gcnt, 0, (size_t)NG * 4, stream);

  prep_weights_kernel<<<1920, 256, 0, stream>>>(e1W, e2W, nW, W1T, W2T, WnT);
  node_embed_kernel<<<NN / 16, 256, 0, stream>>>(x, nodeW, nodeb, hf, h16);
  edge_embed_kernel<<<NE / 16, 256, 0, stream>>>(eattr, edgeW, edgeb, ea16);
  csr_count_kernel<<<NE / 256, 256, 0, stream>>>(eidx + NE, cnt);
  csr_scan_kernel<<<1, 1024, 0, stream>>>(cnt, starts, cur);
  csr_fill_kernel<<<NE / 256, 256, 0, stream>>>(eidx + NE, cur, eid);

  for (int L = 0; L < 3; ++L) {
    conv_edge_kernel<<<NE / 64, 256, 0, stream>>>(
        h16, ea16, eidx,
        W1T + (size_t)L * 98304, e1b + (size_t)L * 256,
        W2T + (size_t)L * 32768, e2b + (size_t)L * 128, ee2);
    aggr_kernel<<<NN, 64, 0, stream>>>(starts, eid, ee2, aggr16);
    conv_node_kernel<<<(NN + 63) / 64, 256, 0, stream>>>(
        h16, aggr16, WnT + (size_t)L * 32768, nb + (size_t)L * 128, hf);
  }
  pool_kernel<<<NN / 16, 128, 0, stream>>>(hf, batch, gsum, gcnt);
  heads_kernel<<<NG, 128, 0, stream>>>(gsum, gcnt, sW1, sb1, sW2, sb2,
                                       hW, hb, hoW, hob, out);
}

// Round 3
// 2315.049 us; speedup vs baseline: 1.1263x; 1.1263x over previous
//
#include <hip/hip_runtime.h>

typedef _Float16 half_t;
typedef __attribute__((ext_vector_type(8))) _Float16 h8_t;
typedef __attribute__((ext_vector_type(4))) float f4_t;

#define NN      50000
#define NE      800000
#define NG      256
#define NODE_IN 92
#define EDGE_IN 41

__device__ __forceinline__ float softplus_f(float x) {
  return fmaxf(x, 0.0f) + __logf(1.0f + __expf(-fabsf(x)));
}

// ---------- weight prep: fp32 [K][N] -> f16 [N][K] (per conv layer) ----------
__global__ __launch_bounds__(256) void prep_weights_kernel(
    const float* __restrict__ e1W, const float* __restrict__ e2W,
    const float* __restrict__ nW,
    half_t* __restrict__ W1T, half_t* __restrict__ W2T, half_t* __restrict__ WnT)
{
  int idx = blockIdx.x * 256 + threadIdx.x;        // 0 .. 491519 (exact grid)
  if (idx < 294912) {                              // W1T: 3 x 256 x 384
    int i = idx / 98304, rem = idx % 98304;
    int n = rem / 384, k = rem % 384;
    W1T[idx] = (half_t)e1W[i * 98304 + k * 256 + n];
  } else if (idx < 393216) {                       // W2T: 3 x 128 x 256
    int o = idx - 294912;
    int i = o / 32768, rem = o % 32768;
    int n = rem / 256, k = rem % 256;
    W2T[o] = (half_t)e2W[i * 32768 + k * 128 + n];
  } else {                                         // WnT: 3 x 128 x 256
    int o = idx - 393216;
    int i = o / 32768, rem = o % 32768;
    int n = rem / 256, k = rem % 256;
    WnT[o] = (half_t)nW[i * 32768 + k * 128 + n];
  }
}

// ---------- node embedding: h = x @ node_W + node_b (fp32 + f16 copy) ----------
__global__ __launch_bounds__(256) void node_embed_kernel(
    const float* __restrict__ x, const float* __restrict__ W,
    const float* __restrict__ bias, float* __restrict__ hf,
    half_t* __restrict__ h16)
{
  __shared__ float xs[16 * NODE_IN];
  int n0 = blockIdx.x * 16;
  for (int i = threadIdx.x; i < 16 * NODE_IN; i += 256)
    xs[i] = x[(size_t)n0 * NODE_IN + i];
  __syncthreads();
  int ch = threadIdx.x & 127, g = threadIdx.x >> 7;
  float acc[8] = {0.f,0.f,0.f,0.f,0.f,0.f,0.f,0.f};
  for (int k = 0; k < NODE_IN; ++k) {
    float w = W[k * 128 + ch];
    #pragma unroll
    for (int u = 0; u < 8; ++u) acc[u] += xs[(g + 2*u) * NODE_IN + k] * w;
  }
  float bv = bias[ch];
  #pragma unroll
  for (int u = 0; u < 8; ++u) {
    int n = n0 + g + 2*u;
    float v = acc[u] + bv;
    hf[(size_t)n*128 + ch] = v;
    h16[(size_t)n*128 + ch] = (half_t)v;
  }
}

// ---------- edge embedding: ea = edge_attr @ edge_W + edge_b (f16) ----------
__global__ __launch_bounds__(256) void edge_embed_kernel(
    const float* __restrict__ ea, const float* __restrict__ W,
    const float* __restrict__ bias, half_t* __restrict__ ea16)
{
  __shared__ float es[16 * EDGE_IN];
  int e0 = blockIdx.x * 16;
  for (int i = threadIdx.x; i < 16 * EDGE_IN; i += 256)
    es[i] = ea[(size_t)e0 * EDGE_IN + i];
  __syncthreads();
  int ch = threadIdx.x & 127, g = threadIdx.x >> 7;
  float acc[8] = {0.f,0.f,0.f,0.f,0.f,0.f,0.f,0.f};
  for (int k = 0; k < EDGE_IN; ++k) {
    float w = W[k * 128 + ch];
    #pragma unroll
    for (int u = 0; u < 8; ++u) acc[u] += es[(g + 2*u) * EDGE_IN + k] * w;
  }
  float bv = bias[ch];
  #pragma unroll
  for (int u = 0; u < 8; ++u) {
    int e = e0 + g + 2*u;
    ea16[(size_t)e*128 + ch] = (half_t)(acc[u] + bv);
  }
}

// ---------- CSR build (by destination node = edge_index[1]) ----------
__global__ __launch_bounds__(256) void csr_count_kernel(
    const int* __restrict__ col, int* __restrict__ cnt)
{
  int e = blockIdx.x * 256 + threadIdx.x;
  atomicAdd(&cnt[col[e]], 1);
}

__global__ __launch_bounds__(1024) void csr_scan_kernel(
    const int* __restrict__ cnt, int* __restrict__ starts, int* __restrict__ cur)
{
  __shared__ int buf[1024];
  int tid = threadIdx.x;
  int base = 0;
  for (int c = 0; c < 49; ++c) {
    int i = c * 1024 + tid;
    int v = (i < NN) ? cnt[i] : 0;
    buf[tid] = v;
    __syncthreads();
    for (int off = 1; off < 1024; off <<= 1) {
      int t2 = (tid >= off) ? buf[tid - off] : 0;
      __syncthreads();
      buf[tid] += t2;
      __syncthreads();
    }
    int incl = buf[tid];
    int total = buf[1023];
    if (i < NN) { int st = base + incl - v; starts[i] = st; cur[i] = st; }
    base += total;
    __syncthreads();
  }
  if (tid == 0) starts[NN] = base;
}

__global__ __launch_bounds__(256) void csr_fill_kernel(
    const int* __restrict__ col, int* __restrict__ cur, int* __restrict__ eid)
{
  int e = blockIdx.x * 256 + threadIdx.x;
  int pos = atomicAdd(&cur[col[e]], 1);
  eid[pos] = e;
}

// ---------- fused edge MLP (swapped-operand MFMA, full LDS staging):
//   P^T = W1^T · [h_row|h_col|ea]^T ; out^T = W2^T · P^T ; packed 8B stores
__global__ __launch_bounds__(256, 2) void conv_edge_kernel(
    const half_t* __restrict__ h16, const half_t* __restrict__ ea16,
    const int* __restrict__ eidx,
    const half_t* __restrict__ W1T, const float* __restrict__ b1,
    const half_t* __restrict__ W2T, const float* __restrict__ b2,
    half_t* __restrict__ ee2)
{
  __shared__ char smem[64 * 384 * 2];   // 48 KB: A [64edge][384ch] stride 768B; P aliases (stride 512B)
  const int tid = threadIdx.x;
  const int e0 = blockIdx.x * 64;

  // gather [h[row] | h[col] | ea] -> LDS, XOR swizzle on 16B granules
  #pragma unroll
  for (int seg = 0; seg < 3; ++seg) {
    #pragma unroll
    for (int it = 0; it < 4; ++it) {
      int idx = tid + it * 256;         // 0..1023 = 64 edges x 16 chunks(16B)
      int e = idx >> 4, c = idx & 15;
      const half_t* src;
      if (seg == 0)      src = h16  + (size_t)eidx[e0 + e]      * 128 + c * 8;
      else if (seg == 1) src = h16  + (size_t)eidx[NE + e0 + e] * 128 + c * 8;
      else               src = ea16 + (size_t)(e0 + e)          * 128 + c * 8;
      uint4 v = *reinterpret_cast<const uint4*>(src);
      unsigned o = (unsigned)(e * 768 + seg * 256 + c * 16) ^ (unsigned)((e & 7) << 4);
      *reinterpret_cast<uint4*>(smem + o) = v;
    }
  }
  __syncthreads();

  const int lane = tid & 63, wave = tid >> 6;
  const int lr = lane & 15, lg = lane >> 4;

  // GEMM1 (swapped): D[channel][edge]; wave owns channels [wave*64, +64)
  const half_t* W1w = W1T + (size_t)(wave * 64) * 384;
  f4_t acc[4][4] = {};
  for (int ks = 0; ks < 12; ++ks) {
    h8_t a[4], b[4];
    #pragma unroll
    for (int m = 0; m < 4; ++m)
      a[m] = *reinterpret_cast<const h8_t*>(W1w + (size_t)(m * 16 + lr) * 384 + ks * 32 + lg * 8);
    #pragma unroll
    for (int n = 0; n < 4; ++n) {
      int e = n * 16 + lr;
      unsigned o = (unsigned)(e * 768 + ks * 64 + lg * 16) ^ (unsigned)((e & 7) << 4);
      b[n] = *reinterpret_cast<const h8_t*>(smem + o);
    }
    #pragma unroll
    for (int m = 0; m < 4; ++m)
      #pragma unroll
      for (int n = 0; n < 4; ++n)
        acc[m][n] = __builtin_amdgcn_mfma_f32_16x16x32_f16(a[m], b[n], acc[m][n], 0, 0, 0);
  }
  __syncthreads();   // all waves done reading A-tile

  // epilogue1: softplus -> P[edge][256ch] in LDS (packed f16 pairs, b32 writes)
  #pragma unroll
  for (int m = 0; m < 4; ++m) {
    int chb = wave * 64 + m * 16 + lg * 4;
    float bb0 = b1[chb + 0], bb1 = b1[chb + 1], bb2 = b1[chb + 2], bb3 = b1[chb + 3];
    #pragma unroll
    for (int n = 0; n < 4; ++n) {
      int e = n * 16 + lr;
      float v0 = softplus_f(acc[m][n][0] + bb0);
      float v1 = softplus_f(acc[m][n][1] + bb1);
      float v2 = softplus_f(acc[m][n][2] + bb2);
      float v3 = softplus_f(acc[m][n][3] + bb3);
      unsigned p01 = __builtin_bit_cast(unsigned, __builtin_amdgcn_cvt_pkrtz(v0, v1));
      unsigned p23 = __builtin_bit_cast(unsigned, __builtin_amdgcn_cvt_pkrtz(v2, v3));
      unsigned o = (unsigned)(e * 512 + chb * 2) ^ (unsigned)((e & 7) << 4);
      *reinterpret_cast<unsigned*>(smem + o) = p01;
      *reinterpret_cast<unsigned*>(smem + o + 4) = p23;
    }
  }
  __syncthreads();

  // GEMM2 (swapped): D[ch2][edge]; wave owns ch2 [wave*32, +32)
  const half_t* W2w = W2T + (size_t)(wave * 32) * 256;
  f4_t acc2[2][4] = {};
  for (int ks = 0; ks < 8; ++ks) {
    h8_t a2[2], b2v[4];
    #pragma unroll
    for (int m = 0; m < 2; ++m)
      a2[m] = *reinterpret_cast<const h8_t*>(W2w + (size_t)(m * 16 + lr) * 256 + ks * 32 + lg * 8);
    #pragma unroll
    for (int n = 0; n < 4; ++n) {
      int e = n * 16 + lr;
      unsigned o = (unsigned)(e * 512 + ks * 64 + lg * 16) ^ (unsigned)((e & 7) << 4);
      b2v[n] = *reinterpret_cast<const h8_t*>(smem + o);
    }
    #pragma unroll
    for (int m = 0; m < 2; ++m)
      #pragma unroll
      for (int n = 0; n < 4; ++n)
        acc2[m][n] = __builtin_amdgcn_mfma_f32_16x16x32_f16(a2[m], b2v[n], acc2[m][n], 0, 0, 0);
  }

  // epilogue2: softplus -> ee2 direct, packed 8B stores (4 contiguous channels)
  #pragma unroll
  for (int m = 0; m < 2; ++m) {
    int chb = wave * 32 + m * 16 + lg * 4;
    float bb0 = b2[chb + 0], bb1 = b2[chb + 1], bb2 = b2[chb + 2], bb3 = b2[chb + 3];
    #pragma unroll
    for (int n = 0; n < 4; ++n) {
      int e = n * 16 + lr;
      float v0 = softplus_f(acc2[m][n][0] + bb0);
      float v1 = softplus_f(acc2[m][n][1] + bb1);
      float v2 = softplus_f(acc2[m][n][2] + bb2);
      float v3 = softplus_f(acc2[m][n][3] + bb3);
      uint2 pk;
      pk.x = __builtin_bit_cast(unsigned, __builtin_amdgcn_cvt_pkrtz(v0, v1));
      pk.y = __builtin_bit_cast(unsigned, __builtin_amdgcn_cvt_pkrtz(v2, v3));
      *reinterpret_cast<uint2*>(ee2 + (size_t)(e0 + e) * 128 + chb) = pk;
    }
  }
}

// ---------- aggregation: aggr[n] = sum over in-edges of ee2 (CSR gather) ----------
__global__ __launch_bounds__(64) void aggr_kernel(
    const int* __restrict__ starts, const int* __restrict__ eid,
    const half_t* __restrict__ ee2, half_t* __restrict__ aggr16)
{
  int n = blockIdx.x, t = threadIdx.x;
  int s = starts[n], epos = starts[n + 1];
  float a0 = 0.f, a1 = 0.f;
  for (int i = s; i < epos; ++i) {
    int e = eid[i];
    unsigned v = *reinterpret_cast<const unsigned*>(ee2 + (size_t)e * 128 + t * 2);
    union { unsigned u; _Float16 h[2]; } cv; cv.u = v;
    a0 += (float)cv.h[0];
    a1 += (float)cv.h[1];
  }
  union { unsigned u; _Float16 h[2]; } ov;
  ov.h[0] = (_Float16)a0; ov.h[1] = (_Float16)a1;
  *reinterpret_cast<unsigned*>(aggr16 + (size_t)n * 128 + t * 2) = ov.u;
}

// ---------- node update: h = sp([h|aggr] @ Wn + bn) + h ----------
__global__ __launch_bounds__(256, 2) void conv_node_kernel(
    half_t* __restrict__ h16, const half_t* __restrict__ aggr16,
    const half_t* __restrict__ WnT, const float* __restrict__ bn,
    float* __restrict__ hf)
{
  __shared__ char smem[64 * 256 * 2];   // 32 KB A = [h | aggr] f16, swizzled
  const int tid = threadIdx.x;
  const int n0 = blockIdx.x * 64;

  #pragma unroll
  for (int it = 0; it < 8; ++it) {
    int idx = tid + it * 256;          // 0..2047 = 64 rows x 32 chunks
    int r = idx >> 5, c = idx & 31;
    int node = n0 + r;
    uint4 v = make_uint4(0u, 0u, 0u, 0u);
    if (node < NN) {
      const half_t* src = (c < 16) ? (h16   + (size_t)node * 128 + c * 8)
                                   : (aggr16 + (size_t)node * 128 + (c - 16) * 8);
      v = *reinterpret_cast<const uint4*>(src);
    }
    unsigned o = (unsigned)(r * 512 + c * 16) ^ (unsigned)((r & 7) << 4);
    *reinterpret_cast<uint4*>(smem + o) = v;
  }
  __syncthreads();

  const int lane = tid & 63, wave = tid >> 6;
  const int lr = lane & 15, lg = lane >> 4;
  const int c0 = wave * 32;
  f4_t acc[4][2] = {};
  for (int ks = 0; ks < 8; ++ks) {
    h8_t a[4], b[2];
    #pragma unroll
    for (int m = 0; m < 4; ++m) {
      int row = m * 16 + lr;
      unsigned o = (unsigned)(row * 512 + ks * 64 + lg * 16) ^ (unsigned)((row & 7) << 4);
      a[m] = *reinterpret_cast<const h8_t*>(smem + o);
    }
    #pragma unroll
    for (int n = 0; n < 2; ++n) {
      int colw = c0 + n * 16 + lr;
      b[n] = *reinterpret_cast<const h8_t*>(WnT + (size_t)colw * 256 + ks * 32 + lg * 8);
    }
    #pragma unroll
    for (int m = 0; m < 4; ++m)
      #pragma unroll
      for (int n = 0; n < 2; ++n)
        acc[m][n] = __builtin_amdgcn_mfma_f32_16x16x32_f16(a[m], b[n], acc[m][n], 0, 0, 0);
  }
  #pragma unroll
  for (int m = 0; m < 4; ++m)
    #pragma unroll
    for (int n = 0; n < 2; ++n)
      #pragma unroll
      for (int r = 0; r < 4; ++r) {
        int row = m * 16 + lg * 4 + r;
        int col = c0 + n * 16 + lr;
        int node = n0 + row;
        if (node < NN) {
          float v = softplus_f(acc[m][n][r] + bn[col]) + hf[(size_t)node * 128 + col];
          hf[(size_t)node * 128 + col] = v;
          h16[(size_t)node * 128 + col] = (half_t)v;
        }
      }
}

// ---------- mean pool (run-length compressed atomics; batch is sorted) ----------
__global__ __launch_bounds__(128) void pool_kernel(
    const float* __restrict__ hf, const int* __restrict__ batch,
    float* __restrict__ gsum, int* __restrict__ gcnt)
{
  int t = threadIdx.x;
  int n0 = blockIdx.x * 16;
  float acc = 0.f;
  int curb = batch[n0];
  for (int i = 0; i < 16; ++i) {
    int n = n0 + i;
    int b = batch[n];
    if (b != curb) { atomicAdd(&gsum[curb * 128 + t], acc); acc = 0.f; curb = b; }
    acc += hf[(size_t)n * 128 + t];
  }
  atomicAdd(&gsum[curb * 128 + t], acc);
  if (t == 0) {
    int c = 0, cb = batch[n0];
    for (int i = 0; i < 16; ++i) {
      int b = batch[n0 + i];
      if (b != cb) { atomicAdd(&gcnt[cb], c); c = 0; cb = b; }
      ++c;
    }
    atomicAdd(&gcnt[cb], c);
  }
}

// ---------- shared MLP + task heads (one block per graph) ----------
__global__ __launch_bounds__(128) void heads_kernel(
    const float* __restrict__ gsum, const int* __restrict__ gcnt,
    const float* __restrict__ sW1, const float* __restrict__ sb1,
    const float* __restrict__ sW2, const float* __restrict__ sb2,
    const float* __restrict__ hW, const float* __restrict__ hb,
    const float* __restrict__ hoW, const float* __restrict__ hob,
    float* __restrict__ out)
{
  int b = blockIdx.x, t = threadIdx.x;
  __shared__ float va[128], vb[128], vc[128], red[128];
  float inv = 1.0f / fmaxf((float)gcnt[b], 1.0f);
  va[t] = gsum[b * 128 + t] * inv;
  __syncthreads();
  { float a = 0.f;
    for (int k = 0; k < 128; ++k) a += va[k] * sW1[k * 128 + t];
    float r = softplus_f(a + sb1[t]);
    __syncthreads(); vb[t] = r; __syncthreads(); }
  { float a = 0.f;
    for (int k = 0; k < 128; ++k) a += vb[k] * sW2[k * 128 + t];
    float r = softplus_f(a + sb2[t]);
    __syncthreads(); va[t] = r; __syncthreads(); }   // va = g2 (kept live)
  for (int p = 0; p < 3; ++p) {
    { float a = 0.f;
      for (int k = 0; k < 128; ++k) a += va[k] * hW[((p * 2 + 0) * 128 + k) * 128 + t];
      float r = softplus_f(a + hb[(p * 2 + 0) * 128 + t]);
      __syncthreads(); vb[t] = r; __syncthreads(); }
    { float a = 0.f;
      for (int k = 0; k < 128; ++k) a += vb[k] * hW[((p * 2 + 1) * 128 + k) * 128 + t];
      float r = softplus_f(a + hb[(p * 2 + 1) * 128 + t]);
      __syncthreads(); vc[t] = r; __syncthreads(); }
    red[t] = vc[t] * hoW[p * 128 + t];
    __syncthreads();
    for (int s = 64; s > 0; s >>= 1) {
      if (t < s) red[t] += red[t + s];
      __syncthreads();
    }
    if (t == 0) out[p * NG + b] = red[0] + hob[p];
    __syncthreads();
  }
}

extern "C" void kernel_launch(void* const* d_in, const int* in_sizes, int n_in,
                              void* d_out, int out_size, void* d_ws, size_t ws_size,
                              hipStream_t stream)
{
  const float* x     = (const float*)d_in[0];
  const float* eattr = (const float*)d_in[1];
  const float* nodeW = (const float*)d_in[2];
  const float* nodeb = (const float*)d_in[3];
  const float* edgeW = (const float*)d_in[4];
  const float* edgeb = (const float*)d_in[5];
  const float* e1W   = (const float*)d_in[6];
  const float* e1b   = (const float*)d_in[7];
  const float* e2W   = (const float*)d_in[8];
  const float* e2b   = (const float*)d_in[9];
  const float* nW    = (const float*)d_in[10];
  const float* nb    = (const float*)d_in[11];
  const float* sW1   = (const float*)d_in[12];
  const float* sb1   = (const float*)d_in[13];
  const float* sW2   = (const float*)d_in[14];
  const float* sb2   = (const float*)d_in[15];
  const float* hW    = (const float*)d_in[16];
  const float* hb    = (const float*)d_in[17];
  const float* hoW   = (const float*)d_in[18];
  const float* hob   = (const float*)d_in[19];
  const int*   eidx  = (const int*)d_in[20];
  const int*   batch = (const int*)d_in[21];
  float* out = (float*)d_out;

  char* base = (char*)d_ws;
  size_t woff = 0;
  auto alloc = [&](size_t bytes) -> char* {
    char* r = base + woff;
    woff = (woff + bytes + 255) & ~(size_t)255;
    return r;
  };
  float*  hf     = (float*) alloc((size_t)NN * 128 * 4);
  half_t* h16    = (half_t*)alloc((size_t)NN * 128 * 2);
  half_t* ea16   = (half_t*)alloc((size_t)NE * 128 * 2);
  half_t* ee2    = (half_t*)alloc((size_t)NE * 128 * 2);
  half_t* aggr16 = (half_t*)alloc((size_t)NN * 128 * 2);
  half_t* W1T    = (half_t*)alloc((size_t)3 * 256 * 384 * 2);
  half_t* W2T    = (half_t*)alloc((size_t)3 * 128 * 256 * 2);
  half_t* WnT    = (half_t*)alloc((size_t)3 * 128 * 256 * 2);
  int* cnt    = (int*)alloc((size_t)NN * 4);
  int* starts = (int*)alloc((size_t)(NN + 1) * 4);
  int* cur    = (int*)alloc((size_t)NN * 4);
  int* eid    = (int*)alloc((size_t)NE * 4);
  float* gsum = (float*)alloc((size_t)NG * 128 * 4);
  int*   gcnt = (int*)alloc((size_t)NG * 4);
  if (woff > ws_size) return;   // workspace too small: launch nothing (fail loud)

  hipMemsetAsync(cnt, 0, (size_t)NN * 4, stream);
  hipMemsetAsync(gsum, 0, (size_t)NG * 128 * 4, stream);
  hipMemsetAsync(gcnt, 0, (size_t)NG * 4, stream);

  prep_weights_kernel<<<1920, 256, 0, stream>>>(e1W, e2W, nW, W1T, W2T, WnT);
  node_embed_kernel<<<NN / 16, 256, 0, stream>>>(x, nodeW, nodeb, hf, h16);
  edge_embed_kernel<<<NE / 16, 256, 0, stream>>>(eattr, edgeW, edgeb, ea16);
  csr_count_kernel<<<NE / 256, 256, 0, stream>>>(eidx + NE, cnt);
  csr_scan_kernel<<<1, 1024, 0, stream>>>(cnt, starts, cur);
  csr_fill_kernel<<<NE / 256, 256, 0, stream>>>(eidx + NE, cur, eid);

  for (int L = 0; L < 3; ++L) {
    conv_edge_kernel<<<NE / 64, 256, 0, stream>>>(
        h16, ea16, eidx,
        W1T + (size_t)L * 98304, e1b + (size_t)L * 256,
        W2T + (size_t)L * 32768, e2b + (size_t)L * 128, ee2);
    aggr_kernel<<<NN, 64, 0, stream>>>(starts, eid, ee2, aggr16);
    conv_node_kernel<<<(NN + 63) / 64, 256, 0, stream>>>(
        h16, aggr16, WnT + (size_t)L * 32768, nb + (size_t)L * 128, hf);
  }
  pool_kernel<<<NN / 16, 128, 0, stream>>>(hf, batch, gsum, gcnt);
  heads_kernel<<<NG, 128, 0, stream>>>(gsum, gcnt, sW1, sb1, sW2, sb2,
                                       hW, hb, hoW, hob, out);
}